// Round 8
// baseline (180.953 us; speedup 1.0000x reference)
//
#include <hip/hip_runtime.h>
#include <stdint.h>
#include <math.h>

#define BATCH 16
#define NNODE 2048
#define DDIM  64
#define NEDGE 32768
#define SEG   32            // slots per quarter-scan segment (mean 8; P(>32)~1e-12)
#define SLOTS 128           // 4*SEG slots per row
#define NROWS (BATCH*NNODE) // 32768
#define RPB   64            // rows per k_build block

// ---------------- kernel 1: LDS-bucketed edge build (quarter-scan) ------
// Round 6/7 showed k_build occupancy-starved: now 4 blocks per row-group,
// each scanning a QUARTER of the edge list into its own SEG-slot segment.
// Same total scan traffic (each edge endpoint tested by 32 row-groups),
// grid 2048 (8 blocks/CU), LDS 16.5 KB. Batch-pinned swizzle keeps each
// batch's 384 KB edge list in one XCD's L2. prio: pass1 -> e, pass2 -> E+e.
__global__ void k_build(const int* __restrict__ ei, const float* __restrict__ m,
                        uint32_t* __restrict__ cnt4, uint2* __restrict__ entries) {
    __shared__ uint32_t cntS[RPB];
    __shared__ uint32_t keyS[RPB][SEG];   // col | prio<<11
    __shared__ float    valS[RPB][SEG];

    int b  = blockIdx.x & 15;             // batch (XCD-pinned)
    int gh = blockIdx.x >> 4;             // 0..127: row-group*4 + quarter
    int r0 = (gh >> 2) * RPB;             // first owned row
    int q  = gh & 3;                      // which quarter of the edge list
    int t  = threadIdx.x;

    if (t < RPB) cntS[t] = 0u;
    __syncthreads();

    const int*   eb = ei + (size_t)b * 2 * NEDGE;
    const float* mb = m  + (size_t)b * NEDGE;
    int e0 = q * (NEDGE / 4);

    for (int i = 0; i < 8; ++i) {                  // 8 x 1024 edges (quarter)
        int e4 = e0 + i * 1024 + t * 4;
        int4   s4 = *(const int4*)(eb + e4);
        int4   d4 = *(const int4*)(eb + NEDGE + e4);
        float4 m4 = *(const float4*)(mb + e4);
        #pragma unroll
        for (int j = 0; j < 4; ++j) {
            int   src = j == 0 ? s4.x : j == 1 ? s4.y : j == 2 ? s4.z : s4.w;
            int   dst = j == 0 ? d4.x : j == 1 ? d4.y : j == 2 ? d4.z : d4.w;
            float mv  = j == 0 ? m4.x : j == 1 ? m4.y : j == 2 ? m4.z : m4.w;
            int e  = e4 + j;
            int rs = src - r0;
            if ((unsigned)rs < RPB) {              // row src, col dst, prio e
                uint32_t p = atomicAdd(&cntS[rs], 1u);
                if (p < SEG) { keyS[rs][p] = (uint32_t)dst | ((uint32_t)e << 11); valS[rs][p] = mv; }
            }
            int rd = dst - r0;
            if ((unsigned)rd < RPB) {              // row dst, col src, prio E+e
                uint32_t p = atomicAdd(&cntS[rd], 1u);
                if (p < SEG) { keyS[rd][p] = (uint32_t)src | ((uint32_t)(NEDGE + e) << 11); valS[rd][p] = mv; }
            }
        }
    }
    __syncthreads();

    // coalesced write-out: lanes 0-31 row 2rr, lanes 32-63 row 2rr+1
    int lane = t & 63;
    int wid  = t >> 6;
    int pos  = lane & 31;
    int sub  = lane >> 5;
    for (int rr = 0; rr < 8; ++rr) {
        int r  = wid * 16 + rr * 2 + sub;
        int rg = b * NNODE + r0 + r;
        int k  = (int)min(cntS[r], (uint32_t)SEG);
        size_t base = (size_t)rg * SLOTS + q * SEG;
        if (pos < k)
            entries[base + pos] = make_uint2(keyS[r][pos], __float_as_uint(valS[r][pos]));
        if (pos == 0) cnt4[rg * 4 + q] = (uint32_t)k;
    }
}

// ---------------- kernel 2: per-row dedupe + degree + compaction --------
// 4 segments map to halves of 2 registers; kill loops bounded by exact
// per-segment counts (invalid lanes never broadcast). Compacts to [0,k).
__global__ void k_dedupe(const uint32_t* __restrict__ cnt4, uint2* __restrict__ entries,
                         uint32_t* __restrict__ cnt_fin,
                         float* __restrict__ dis, float* __restrict__ self) {
    int b    = blockIdx.x & 15;
    int w    = b * NNODE + (blockIdx.x >> 4) * 4 + (threadIdx.x >> 6);
    int lane = threadIdx.x & 63;
    uint4 kq = ((const uint4*)cnt4)[w];
    int k0 = (int)kq.x, k1 = (int)kq.y, k2 = (int)kq.z, k3 = (int)kq.w;
    size_t base = (size_t)w * SLOTS;
    int pos = lane & 31;
    int klo = (lane < 32) ? k0 : k1;
    int khi = (lane < 32) ? k2 : k3;

    uint32_t key0 = 0u, key1 = 0u;
    float v0 = 0.f, v1 = 0.f;
    bool a0 = pos < klo;
    bool a1 = pos < khi;
    if (a0) { uint2 kv = entries[base + lane];      key0 = kv.x; v0 = __uint_as_float(kv.y); }
    if (a1) { uint2 kv = entries[base + 64 + lane]; key1 = kv.x; v1 = __uint_as_float(kv.y); }
    uint32_t c0 = key0 & 2047u, p0 = key0 >> 11;
    uint32_t c1 = key1 & 2047u, p1 = key1 >> 11;

    #define KILL(ks) { uint32_t cs = (ks) & 2047u, ps = (ks) >> 11; \
        a0 = a0 && !((c0 == cs) && (p0 < ps)); \
        a1 = a1 && !((c1 == cs) && (p1 < ps)); }
    for (int s = 0; s < k0; ++s) KILL(__builtin_amdgcn_readlane(key0, s))
    for (int s = 0; s < k1; ++s) KILL(__builtin_amdgcn_readlane(key0, 32 + s))
    for (int s = 0; s < k2; ++s) KILL(__builtin_amdgcn_readlane(key1, s))
    for (int s = 0; s < k3; ++s) KILL(__builtin_amdgcn_readlane(key1, 32 + s))
    #undef KILL

    float sum = (a0 ? v0 : 0.f) + (a1 ? v1 : 0.f);
    for (int off = 32; off; off >>= 1) sum += __shfl_xor(sum, off, 64);
    float deg = fmaxf(1.0f + sum, 1e-6f);          // +1: identity diagonal
    if (lane == 0) {
        float di = 1.0f / sqrtf(deg);
        dis[w]  = di;
        self[w] = di * di;
    }

    unsigned long long m0 = __ballot(a0);
    unsigned long long m1 = __ballot(a1);
    unsigned long long below = (1ull << lane) - 1ull;
    int n0 = __popcll(m0);
    if (a0) entries[base + __popcll(m0 & below)]      = make_uint2(key0, __float_as_uint(v0));
    if (a1) entries[base + n0 + __popcll(m1 & below)] = make_uint2(key1, __float_as_uint(v1));
    if (lane == 0) cnt_fin[w] = (uint32_t)(n0 + __popcll(m1));
}

// ---------------- kernel 3: fused SpMM + (X @ W^T) + optional GELU ------
// One wave per 2 rows. Paired-float2 gather: lanes 0-31 process even
// entries, lanes 32-63 odd entries, each lane covering dims (2p, 2p+1) via
// one dwordx2 -> half the gather loads of the dword scheme at same bytes.
// Normalization (dis_r * val * dis_c) is applied on the fly (k_norm pass
// eliminated): zero-initialized invalid slots give w = 0, so padding to an
// even entry count is harmless.
__global__ void k_layer(const float* __restrict__ Xin, const float* __restrict__ W,
                        float* __restrict__ Xout,
                        const uint32_t* __restrict__ cnt_fin, const uint2* __restrict__ entries,
                        const float* __restrict__ dis, const float* __restrict__ self,
                        int dogelu) {
    __shared__ float WT[64 * 65];     // WT[d*65+e] = W[e*64+d]; +1 pad: conflict-free
    int Lb = blockIdx.x;              // 4096 blocks
    int b  = Lb & 15;                 // batch -> XCD swizzle
    int rb = Lb >> 4;
    int t  = threadIdx.x;

    #pragma unroll
    for (int i = 0; i < 16; ++i) {
        int idx = i * 256 + t;
        WT[(idx & 63) * 65 + (idx >> 6)] = W[idx];
    }
    __syncthreads();

    int lane = t & 63;
    int wid  = t >> 6;
    bool hi  = lane >= 32;
    int pairOff = (lane & 31) * 8;    // byte offset of this lane's dim pair
    const char*  XbB  = (const char*)(Xin + (size_t)b * NNODE * DDIM);
    const float* disB = dis + (b << 11);

    float r0x = 0.f, r0y = 0.f, r1x = 0.f, r1y = 0.f;
    #pragma unroll
    for (int rr = 0; rr < 2; ++rr) {
        int row = rb * 8 + wid * 2 + rr;
        int rg  = b * NNODE + row;
        int k   = (int)cnt_fin[rg];
        size_t base = (size_t)rg * SLOTS;

        uint32_t kA = 0u, vA = 0u, kB = 0u, vB = 0u;
        if (lane < k)      { uint2 kv = entries[base + lane];      kA = kv.x; vA = kv.y; }
        if (lane + 64 < k) { uint2 kv = entries[base + 64 + lane]; kB = kv.x; vB = kv.y; }

        // on-the-fly normalization (in-lane, before broadcast)
        float dr = disB[row];
        int colA = (int)(kA & 2047u);
        uint32_t offA = (uint32_t)colA << 8;
        uint32_t wAu  = __float_as_uint(__uint_as_float(vA) * dr * disB[colA]);
        int colB = (int)(kB & 2047u);
        uint32_t offB = (uint32_t)colB << 8;
        uint32_t wBu  = __float_as_uint(__uint_as_float(vB) * dr * disB[colB]);

        float ax0 = 0.f, ay0 = 0.f, ax1 = 0.f, ay1 = 0.f;
        float ax2 = 0.f, ay2 = 0.f, ax3 = 0.f, ay3 = 0.f;
        int ke = k < 64 ? k : 64;
        int e = 0;
        #define P(i, AX, AY) { \
            uint32_t oe = __builtin_amdgcn_readlane(offA, e + 2*i); \
            uint32_t oo = __builtin_amdgcn_readlane(offA, e + 2*i + 1); \
            uint32_t we = __builtin_amdgcn_readlane(wAu,  e + 2*i); \
            uint32_t wo = __builtin_amdgcn_readlane(wAu,  e + 2*i + 1); \
            uint32_t o  = hi ? oo : oe; \
            float wsel  = __uint_as_float(hi ? wo : we); \
            float2 x = *(const float2*)(XbB + o + pairOff); \
            AX = fmaf(wsel, x.x, AX); AY = fmaf(wsel, x.y, AY); }
        for (; e + 16 <= ke; e += 16) {            // 8 paired dwordx2 in flight
            P(0, ax0, ay0) P(1, ax1, ay1) P(2, ax2, ay2) P(3, ax3, ay3)
            P(4, ax0, ay0) P(5, ax1, ay1) P(6, ax2, ay2) P(7, ax3, ay3)
        }
        for (; e < ke; e += 2) {                   // trailing pairs (zero-padded)
            P(0, ax0, ay0)
        }
        #undef P
        float ax = (ax0 + ax1) + (ax2 + ax3);
        float ay = (ay0 + ay1) + (ay2 + ay3);
        // combine halves: every lane then holds full sums for dims (2p,2p+1)
        ax += __shfl_xor(ax, 32, 64);
        ay += __shfl_xor(ay, 32, 64);
        // rare tail k>64 (duplicated across halves, post-combine)
        for (int e2 = 64; e2 < k; ++e2) {
            uint32_t o  = __builtin_amdgcn_readlane(offB, e2 - 64);
            float    wv = __uint_as_float(__builtin_amdgcn_readlane(wBu, e2 - 64));
            float2 x = *(const float2*)(XbB + o + pairOff);
            ax = fmaf(wv, x.x, ax); ay = fmaf(wv, x.y, ay);
        }
        // identity term
        float2 xr = *(const float2*)(XbB + ((uint32_t)row << 8) + pairOff);
        float sf = self[rg];
        ax = fmaf(sf, xr.x, ax); ay = fmaf(sf, xr.y, ay);
        if (rr == 0) { r0x = ax; r0y = ay; } else { r1x = ax; r1y = ay; }
    }

    // y[lane] = sum_d s_d * W[lane][d]; s_{2j} at lane j (.x), s_{2j+1} (.y)
    float ya = 0.f, yb = 0.f;
    #pragma unroll
    for (int j = 0; j < 32; ++j) {
        float wt0 = WT[(2 * j)     * 65 + lane];
        float wt1 = WT[(2 * j + 1) * 65 + lane];
        ya = fmaf(__uint_as_float(__builtin_amdgcn_readlane(__float_as_uint(r0x), j)), wt0, ya);
        ya = fmaf(__uint_as_float(__builtin_amdgcn_readlane(__float_as_uint(r0y), j)), wt1, ya);
        yb = fmaf(__uint_as_float(__builtin_amdgcn_readlane(__float_as_uint(r1x), j)), wt0, yb);
        yb = fmaf(__uint_as_float(__builtin_amdgcn_readlane(__float_as_uint(r1y), j)), wt1, yb);
    }
    if (dogelu) {
        ya = 0.5f * ya * (1.0f + erff(ya * 0.70710678118654752440f));
        yb = 0.5f * yb * (1.0f + erff(yb * 0.70710678118654752440f));
    }
    int row0 = rb * 8 + wid * 2;
    Xout[((size_t)b * NNODE + row0)     * DDIM + lane] = ya;
    Xout[((size_t)b * NNODE + row0 + 1) * DDIM + lane] = yb;
}

// ---------------- launch ------------------------------------------------
extern "C" void kernel_launch(void* const* d_in, const int* in_sizes, int n_in,
                              void* d_out, int out_size, void* d_ws, size_t ws_size,
                              hipStream_t stream) {
    const float* H  = (const float*)d_in[0];   // (B,N,D) fp32
    const int*   ei = (const int*)d_in[1];     // (B,2,E) int32
    const float* m  = (const float*)d_in[2];   // (B,E) fp32
    const float* W  = (const float*)d_in[3];   // (L,D,D) fp32
    float* out = (float*)d_out;                // (B,N,D) fp32

    char* ws = (char*)d_ws;
    uint32_t* cnt4    = (uint32_t*)ws;                                        // 512 KB (4 counts/row)
    uint32_t* cnt_fin = (uint32_t*)(ws + (512 << 10));                        // 128 KB
    float*    dis     = (float*)(ws + (640 << 10));                           // 128 KB
    float*    self    = (float*)(ws + (768 << 10));                           // 128 KB
    uint2*    entries = (uint2*)(ws + (896 << 10));                           // 32768*128*8 = 32 MB
    float*    X2      = (float*)(ws + (896 << 10) + (size_t)NROWS * SLOTS * 8);  // 8 MB

    k_build <<<BATCH * (NNODE / RPB) * 4, 256, 0, stream>>>(ei, m, cnt4, entries);
    k_dedupe<<<NROWS / 4, 256, 0, stream>>>(cnt4, entries, cnt_fin, dis, self);
    k_layer <<<4096, 256, 0, stream>>>(H,  W,        X2,  cnt_fin, entries, dis, self, 1);
    k_layer <<<4096, 256, 0, stream>>>(X2, W + 4096, out, cnt_fin, entries, dis, self, 0);
}

// Round 9
// 173.798 us; speedup vs baseline: 1.0412x; 1.0412x over previous
//
#include <hip/hip_runtime.h>
#include <stdint.h>
#include <math.h>

#define BATCH 16
#define NNODE 2048
#define DDIM  64
#define NEDGE 32768
#define SEG   32            // slots per quarter-scan segment (mean 8; P(>32)~1e-12)
#define SLOTS 128           // 4*SEG slots per row
#define NROWS (BATCH*NNODE) // 32768
#define RPB   64            // rows per k_build block

// ---------------- kernel 1: LDS-bucketed edge build (quarter-scan) ------
// (round-8 verbatim) 4 blocks per row-group, each scanning a quarter of the
// edge list into its own SEG-slot segment. Batch-pinned swizzle keeps each
// batch's 384 KB edge list in one XCD's L2. prio: pass1 -> e, pass2 -> E+e.
__global__ void k_build(const int* __restrict__ ei, const float* __restrict__ m,
                        uint32_t* __restrict__ cnt4, uint2* __restrict__ entries) {
    __shared__ uint32_t cntS[RPB];
    __shared__ uint32_t keyS[RPB][SEG];   // col | prio<<11
    __shared__ float    valS[RPB][SEG];

    int b  = blockIdx.x & 15;             // batch (XCD-pinned)
    int gh = blockIdx.x >> 4;             // 0..127: row-group*4 + quarter
    int r0 = (gh >> 2) * RPB;             // first owned row
    int q  = gh & 3;                      // which quarter of the edge list
    int t  = threadIdx.x;

    if (t < RPB) cntS[t] = 0u;
    __syncthreads();

    const int*   eb = ei + (size_t)b * 2 * NEDGE;
    const float* mb = m  + (size_t)b * NEDGE;
    int e0 = q * (NEDGE / 4);

    for (int i = 0; i < 8; ++i) {                  // 8 x 1024 edges (quarter)
        int e4 = e0 + i * 1024 + t * 4;
        int4   s4 = *(const int4*)(eb + e4);
        int4   d4 = *(const int4*)(eb + NEDGE + e4);
        float4 m4 = *(const float4*)(mb + e4);
        #pragma unroll
        for (int j = 0; j < 4; ++j) {
            int   src = j == 0 ? s4.x : j == 1 ? s4.y : j == 2 ? s4.z : s4.w;
            int   dst = j == 0 ? d4.x : j == 1 ? d4.y : j == 2 ? d4.z : d4.w;
            float mv  = j == 0 ? m4.x : j == 1 ? m4.y : j == 2 ? m4.z : m4.w;
            int e  = e4 + j;
            int rs = src - r0;
            if ((unsigned)rs < RPB) {              // row src, col dst, prio e
                uint32_t p = atomicAdd(&cntS[rs], 1u);
                if (p < SEG) { keyS[rs][p] = (uint32_t)dst | ((uint32_t)e << 11); valS[rs][p] = mv; }
            }
            int rd = dst - r0;
            if ((unsigned)rd < RPB) {              // row dst, col src, prio E+e
                uint32_t p = atomicAdd(&cntS[rd], 1u);
                if (p < SEG) { keyS[rd][p] = (uint32_t)src | ((uint32_t)(NEDGE + e) << 11); valS[rd][p] = mv; }
            }
        }
    }
    __syncthreads();

    // coalesced write-out: lanes 0-31 row 2rr, lanes 32-63 row 2rr+1
    int lane = t & 63;
    int wid  = t >> 6;
    int pos  = lane & 31;
    int sub  = lane >> 5;
    for (int rr = 0; rr < 8; ++rr) {
        int r  = wid * 16 + rr * 2 + sub;
        int rg = b * NNODE + r0 + r;
        int k  = (int)min(cntS[r], (uint32_t)SEG);
        size_t base = (size_t)rg * SLOTS + q * SEG;
        if (pos < k)
            entries[base + pos] = make_uint2(keyS[r][pos], __float_as_uint(valS[r][pos]));
        if (pos == 0) cnt4[rg * 4 + q] = (uint32_t)k;
    }
}

// ---------------- kernel 2: per-row dedupe + degree + compaction --------
// (round-8 verbatim) 4 segments map to halves of 2 registers; kill loops
// bounded by exact per-segment counts. Compacts to [0,k).
__global__ void k_dedupe(const uint32_t* __restrict__ cnt4, uint2* __restrict__ entries,
                         uint32_t* __restrict__ cnt_fin,
                         float* __restrict__ dis, float* __restrict__ self) {
    int b    = blockIdx.x & 15;
    int w    = b * NNODE + (blockIdx.x >> 4) * 4 + (threadIdx.x >> 6);
    int lane = threadIdx.x & 63;
    uint4 kq = ((const uint4*)cnt4)[w];
    int k0 = (int)kq.x, k1 = (int)kq.y, k2 = (int)kq.z, k3 = (int)kq.w;
    size_t base = (size_t)w * SLOTS;
    int pos = lane & 31;
    int klo = (lane < 32) ? k0 : k1;
    int khi = (lane < 32) ? k2 : k3;

    uint32_t key0 = 0u, key1 = 0u;
    float v0 = 0.f, v1 = 0.f;
    bool a0 = pos < klo;
    bool a1 = pos < khi;
    if (a0) { uint2 kv = entries[base + lane];      key0 = kv.x; v0 = __uint_as_float(kv.y); }
    if (a1) { uint2 kv = entries[base + 64 + lane]; key1 = kv.x; v1 = __uint_as_float(kv.y); }
    uint32_t c0 = key0 & 2047u, p0 = key0 >> 11;
    uint32_t c1 = key1 & 2047u, p1 = key1 >> 11;

    #define KILL(ks) { uint32_t cs = (ks) & 2047u, ps = (ks) >> 11; \
        a0 = a0 && !((c0 == cs) && (p0 < ps)); \
        a1 = a1 && !((c1 == cs) && (p1 < ps)); }
    for (int s = 0; s < k0; ++s) KILL(__builtin_amdgcn_readlane(key0, s))
    for (int s = 0; s < k1; ++s) KILL(__builtin_amdgcn_readlane(key0, 32 + s))
    for (int s = 0; s < k2; ++s) KILL(__builtin_amdgcn_readlane(key1, s))
    for (int s = 0; s < k3; ++s) KILL(__builtin_amdgcn_readlane(key1, 32 + s))
    #undef KILL

    float sum = (a0 ? v0 : 0.f) + (a1 ? v1 : 0.f);
    for (int off = 32; off; off >>= 1) sum += __shfl_xor(sum, off, 64);
    float deg = fmaxf(1.0f + sum, 1e-6f);          // +1: identity diagonal
    if (lane == 0) {
        float di = 1.0f / sqrtf(deg);
        dis[w]  = di;
        self[w] = di * di;
    }

    unsigned long long m0 = __ballot(a0);
    unsigned long long m1 = __ballot(a1);
    unsigned long long below = (1ull << lane) - 1ull;
    int n0 = __popcll(m0);
    if (a0) entries[base + __popcll(m0 & below)]      = make_uint2(key0, __float_as_uint(v0));
    if (a1) entries[base + n0 + __popcll(m1 & below)] = make_uint2(key1, __float_as_uint(v1));
    if (lane == 0) cnt_fin[w] = (uint32_t)(n0 + __popcll(m1));
}

// ---------------- kernel 3: fused SpMM + (X @ W^T) + optional GELU ------
// Round-7 gather structure (dword loads, 16 independent in flight, 4 acc
// chains) — round-8's paired-float2 scheme was the suspected regression.
// Normalization (dis_r * val * dis_c) applied in-lane before broadcast
// (k_norm pass stays eliminated). Fused W-loop serves both rows.
__global__ void k_layer(const float* __restrict__ Xin, const float* __restrict__ W,
                        float* __restrict__ Xout,
                        const uint32_t* __restrict__ cnt_fin, const uint2* __restrict__ entries,
                        const float* __restrict__ dis, const float* __restrict__ self,
                        int dogelu) {
    __shared__ float WT[64 * 65];     // WT[d*65+e] = W[e*64+d]; +1 pad: conflict-free
    int Lb = blockIdx.x;              // 4096 blocks
    int b  = Lb & 15;                 // batch -> XCD swizzle
    int rb = Lb >> 4;
    int t  = threadIdx.x;

    #pragma unroll
    for (int i = 0; i < 16; ++i) {
        int idx = i * 256 + t;
        WT[(idx & 63) * 65 + (idx >> 6)] = W[idx];
    }
    __syncthreads();

    int lane = t & 63;
    int wid  = t >> 6;
    const float* Xb   = Xin + (size_t)b * NNODE * DDIM;
    const char*  Xc   = (const char*)Xb + lane * 4;
    const float* disB = dis + (b << 11);

    float accv[2];
    #pragma unroll
    for (int rr = 0; rr < 2; ++rr) {
        int row = rb * 8 + wid * 2 + rr;
        int rg  = b * NNODE + row;
        int k   = (int)cnt_fin[rg];
        size_t base = (size_t)rg * SLOTS;

        uint32_t kA = 0u, vA = 0u, kB = 0u, vB = 0u;
        if (lane < k)      { uint2 kv = entries[base + lane];      kA = kv.x; vA = kv.y; }
        if (lane + 64 < k) { uint2 kv = entries[base + 64 + lane]; kB = kv.x; vB = kv.y; }

        // in-lane normalization before broadcast: off = col*256, w = dr*val*dis[col]
        float dr = disB[row];
        int   colA = (int)(kA & 2047u);
        uint32_t offA = (uint32_t)colA << 8;
        uint32_t wAu  = __float_as_uint(__uint_as_float(vA) * dr * disB[colA]);
        int   colB = (int)(kB & 2047u);
        uint32_t offB = (uint32_t)colB << 8;
        uint32_t wBu  = __float_as_uint(__uint_as_float(vB) * dr * disB[colB]);

        float acc0 = self[rg] * Xb[(size_t)row * DDIM + lane];   // identity term
        float acc1 = 0.f, acc2 = 0.f, acc3 = 0.f;

        int k0 = k < 64 ? k : 64;
        int e = 0;
        for (; e + 16 <= k0; e += 16) {            // 16 loads in flight
            float xv0, xv1, xv2, xv3, xv4, xv5, xv6, xv7;
            float xv8, xv9, xva, xvb, xvc, xvd, xve, xvf;
            float w0, w1, w2, w3, w4, w5, w6, w7;
            float w8, w9, wa, wb, wc, wd, we, wf;
            #define G(idx, X, Wv) { \
                uint32_t o = __builtin_amdgcn_readlane(offA, e + idx); \
                Wv = __uint_as_float(__builtin_amdgcn_readlane(wAu, e + idx)); \
                X = *(const float*)(Xc + o); }
            G(0, xv0, w0)  G(1, xv1, w1)  G(2, xv2, w2)  G(3, xv3, w3)
            G(4, xv4, w4)  G(5, xv5, w5)  G(6, xv6, w6)  G(7, xv7, w7)
            G(8, xv8, w8)  G(9, xv9, w9)  G(10, xva, wa) G(11, xvb, wb)
            G(12, xvc, wc) G(13, xvd, wd) G(14, xve, we) G(15, xvf, wf)
            #undef G
            acc0 = fmaf(w0, xv0, acc0); acc1 = fmaf(w1, xv1, acc1);
            acc2 = fmaf(w2, xv2, acc2); acc3 = fmaf(w3, xv3, acc3);
            acc0 = fmaf(w4, xv4, acc0); acc1 = fmaf(w5, xv5, acc1);
            acc2 = fmaf(w6, xv6, acc2); acc3 = fmaf(w7, xv7, acc3);
            acc0 = fmaf(w8, xv8, acc0); acc1 = fmaf(w9, xv9, acc1);
            acc2 = fmaf(wa, xva, acc2); acc3 = fmaf(wb, xvb, acc3);
            acc0 = fmaf(wc, xvc, acc0); acc1 = fmaf(wd, xvd, acc1);
            acc2 = fmaf(we, xve, acc2); acc3 = fmaf(wf, xvf, acc3);
        }
        for (; e + 4 <= k0; e += 4) {
            uint32_t o0 = __builtin_amdgcn_readlane(offA, e);
            uint32_t o1 = __builtin_amdgcn_readlane(offA, e + 1);
            uint32_t o2 = __builtin_amdgcn_readlane(offA, e + 2);
            uint32_t o3 = __builtin_amdgcn_readlane(offA, e + 3);
            float w0 = __uint_as_float(__builtin_amdgcn_readlane(wAu, e));
            float w1 = __uint_as_float(__builtin_amdgcn_readlane(wAu, e + 1));
            float w2 = __uint_as_float(__builtin_amdgcn_readlane(wAu, e + 2));
            float w3 = __uint_as_float(__builtin_amdgcn_readlane(wAu, e + 3));
            acc0 = fmaf(w0, *(const float*)(Xc + o0), acc0);
            acc1 = fmaf(w1, *(const float*)(Xc + o1), acc1);
            acc2 = fmaf(w2, *(const float*)(Xc + o2), acc2);
            acc3 = fmaf(w3, *(const float*)(Xc + o3), acc3);
        }
        for (; e < k0; ++e) {
            uint32_t o = __builtin_amdgcn_readlane(offA, e);
            float wv = __uint_as_float(__builtin_amdgcn_readlane(wAu, e));
            acc0 = fmaf(wv, *(const float*)(Xc + o), acc0);
        }
        for (e = 64; e < k; ++e) {                 // rare tail (k>64)
            uint32_t o = __builtin_amdgcn_readlane(offB, e - 64);
            float wv = __uint_as_float(__builtin_amdgcn_readlane(wBu, e - 64));
            acc1 = fmaf(wv, *(const float*)(Xc + o), acc1);
        }
        accv[rr] = (acc0 + acc1) + (acc2 + acc3);
    }

    // fused W-multiply: one WT read serves both rows
    float sa = accv[0], sb = accv[1];
    float ya = 0.f, yb = 0.f;
    #pragma unroll
    for (int d = 0; d < 64; ++d) {
        float wt = WT[d * 65 + lane];
        ya = fmaf(__uint_as_float(__builtin_amdgcn_readlane(__float_as_uint(sa), d)), wt, ya);
        yb = fmaf(__uint_as_float(__builtin_amdgcn_readlane(__float_as_uint(sb), d)), wt, yb);
    }
    if (dogelu) {
        ya = 0.5f * ya * (1.0f + erff(ya * 0.70710678118654752440f));
        yb = 0.5f * yb * (1.0f + erff(yb * 0.70710678118654752440f));
    }
    int row0 = rb * 8 + wid * 2;
    Xout[((size_t)b * NNODE + row0)     * DDIM + lane] = ya;
    Xout[((size_t)b * NNODE + row0 + 1) * DDIM + lane] = yb;
}

// ---------------- launch ------------------------------------------------
extern "C" void kernel_launch(void* const* d_in, const int* in_sizes, int n_in,
                              void* d_out, int out_size, void* d_ws, size_t ws_size,
                              hipStream_t stream) {
    const float* H  = (const float*)d_in[0];   // (B,N,D) fp32
    const int*   ei = (const int*)d_in[1];     // (B,2,E) int32
    const float* m  = (const float*)d_in[2];   // (B,E) fp32
    const float* W  = (const float*)d_in[3];   // (L,D,D) fp32
    float* out = (float*)d_out;                // (B,N,D) fp32

    char* ws = (char*)d_ws;
    uint32_t* cnt4    = (uint32_t*)ws;                                        // 512 KB (4 counts/row)
    uint32_t* cnt_fin = (uint32_t*)(ws + (512 << 10));                        // 128 KB
    float*    dis     = (float*)(ws + (640 << 10));                           // 128 KB
    float*    self    = (float*)(ws + (768 << 10));                           // 128 KB
    uint2*    entries = (uint2*)(ws + (896 << 10));                           // 32768*128*8 = 32 MB
    float*    X2      = (float*)(ws + (896 << 10) + (size_t)NROWS * SLOTS * 8);  // 8 MB

    k_build <<<BATCH * (NNODE / RPB) * 4, 256, 0, stream>>>(ei, m, cnt4, entries);
    k_dedupe<<<NROWS / 4, 256, 0, stream>>>(cnt4, entries, cnt_fin, dis, self);
    k_layer <<<4096, 256, 0, stream>>>(H,  W,        X2,  cnt_fin, entries, dis, self, 1);
    k_layer <<<4096, 256, 0, stream>>>(X2, W + 4096, out, cnt_fin, entries, dis, self, 0);
}

// Round 10
// 166.882 us; speedup vs baseline: 1.0843x; 1.0414x over previous
//
#include <hip/hip_runtime.h>
#include <stdint.h>
#include <math.h>

#define BATCH 16
#define NNODE 2048
#define DDIM  64
#define NEDGE 32768
#define SEG   32            // slots per quarter-scan segment (mean 8; P(>32)~1e-11)
#define SLOTS 128           // 4*SEG slots per row
#define NROWS (BATCH*NNODE) // 32768
#define RPB   128           // rows per k_build block (512-thread blocks)

// ---------------- kernel 1: LDS-bucketed edge build (quarter-scan) ------
// RPB=128 + 512-thread blocks: halves total edge-scans (8.4M vs round-8's
// 16.8M) at the same 8 waves/SIMD TLP (1024 blocks x 32.5 KB LDS -> 4
// blocks/CU x 8 waves). Batch-pinned swizzle keeps each batch's 384 KB
// edge list in one XCD's L2. prio: pass1 -> e, pass2 -> E+e; later wins.
__global__ void k_build(const int* __restrict__ ei, const float* __restrict__ m,
                        uint32_t* __restrict__ cnt4, uint2* __restrict__ entries) {
    __shared__ uint32_t cntS[RPB];
    __shared__ uint32_t keyS[RPB][SEG];   // col | prio<<11
    __shared__ float    valS[RPB][SEG];

    int b  = blockIdx.x & 15;             // batch (XCD-pinned)
    int gh = blockIdx.x >> 4;             // 0..63: row-group*4 + quarter
    int r0 = (gh >> 2) * RPB;             // first owned row
    int q  = gh & 3;                      // which quarter of the edge list
    int t  = threadIdx.x;                 // 0..511

    if (t < RPB) cntS[t] = 0u;
    __syncthreads();

    const int*   eb = ei + (size_t)b * 2 * NEDGE;
    const float* mb = m  + (size_t)b * NEDGE;
    int e0 = q * (NEDGE / 4);

    for (int i = 0; i < 4; ++i) {                  // 4 x 2048 edges (quarter)
        int e4 = e0 + i * 2048 + t * 4;
        int4   s4 = *(const int4*)(eb + e4);
        int4   d4 = *(const int4*)(eb + NEDGE + e4);
        float4 m4 = *(const float4*)(mb + e4);
        #pragma unroll
        for (int j = 0; j < 4; ++j) {
            int   src = j == 0 ? s4.x : j == 1 ? s4.y : j == 2 ? s4.z : s4.w;
            int   dst = j == 0 ? d4.x : j == 1 ? d4.y : j == 2 ? d4.z : d4.w;
            float mv  = j == 0 ? m4.x : j == 1 ? m4.y : j == 2 ? m4.z : m4.w;
            int e  = e4 + j;
            int rs = src - r0;
            if ((unsigned)rs < RPB) {              // row src, col dst, prio e
                uint32_t p = atomicAdd(&cntS[rs], 1u);
                if (p < SEG) { keyS[rs][p] = (uint32_t)dst | ((uint32_t)e << 11); valS[rs][p] = mv; }
            }
            int rd = dst - r0;
            if ((unsigned)rd < RPB) {              // row dst, col src, prio E+e
                uint32_t p = atomicAdd(&cntS[rd], 1u);
                if (p < SEG) { keyS[rd][p] = (uint32_t)src | ((uint32_t)(NEDGE + e) << 11); valS[rd][p] = mv; }
            }
        }
    }
    __syncthreads();

    // coalesced write-out: 8 waves x 16 rows; lanes 0-31 row 2rr, 32-63 row 2rr+1
    int lane = t & 63;
    int wid  = t >> 6;                    // 0..7
    int pos  = lane & 31;
    int sub  = lane >> 5;
    for (int rr = 0; rr < 8; ++rr) {
        int r  = wid * 16 + rr * 2 + sub;
        int rg = b * NNODE + r0 + r;
        int k  = (int)min(cntS[r], (uint32_t)SEG);
        size_t base = (size_t)rg * SLOTS + q * SEG;
        if (pos < k)
            entries[base + pos] = make_uint2(keyS[r][pos], __float_as_uint(valS[r][pos]));
        if (pos == 0) cnt4[rg * 4 + q] = (uint32_t)k;
    }
}

// ---------------- kernel 2: per-row dedupe + degree + compaction --------
// (round-9 verbatim) 4 segments map to halves of 2 registers; kill loops
// bounded by exact per-segment counts. Compacts to [0,k).
__global__ void k_dedupe(const uint32_t* __restrict__ cnt4, uint2* __restrict__ entries,
                         uint32_t* __restrict__ cnt_fin,
                         float* __restrict__ dis, float* __restrict__ self) {
    int b    = blockIdx.x & 15;
    int w    = b * NNODE + (blockIdx.x >> 4) * 4 + (threadIdx.x >> 6);
    int lane = threadIdx.x & 63;
    uint4 kq = ((const uint4*)cnt4)[w];
    int k0 = (int)kq.x, k1 = (int)kq.y, k2 = (int)kq.z, k3 = (int)kq.w;
    size_t base = (size_t)w * SLOTS;
    int pos = lane & 31;
    int klo = (lane < 32) ? k0 : k1;
    int khi = (lane < 32) ? k2 : k3;

    uint32_t key0 = 0u, key1 = 0u;
    float v0 = 0.f, v1 = 0.f;
    bool a0 = pos < klo;
    bool a1 = pos < khi;
    if (a0) { uint2 kv = entries[base + lane];      key0 = kv.x; v0 = __uint_as_float(kv.y); }
    if (a1) { uint2 kv = entries[base + 64 + lane]; key1 = kv.x; v1 = __uint_as_float(kv.y); }
    uint32_t c0 = key0 & 2047u, p0 = key0 >> 11;
    uint32_t c1 = key1 & 2047u, p1 = key1 >> 11;

    #define KILL(ks) { uint32_t cs = (ks) & 2047u, ps = (ks) >> 11; \
        a0 = a0 && !((c0 == cs) && (p0 < ps)); \
        a1 = a1 && !((c1 == cs) && (p1 < ps)); }
    for (int s = 0; s < k0; ++s) KILL(__builtin_amdgcn_readlane(key0, s))
    for (int s = 0; s < k1; ++s) KILL(__builtin_amdgcn_readlane(key0, 32 + s))
    for (int s = 0; s < k2; ++s) KILL(__builtin_amdgcn_readlane(key1, s))
    for (int s = 0; s < k3; ++s) KILL(__builtin_amdgcn_readlane(key1, 32 + s))
    #undef KILL

    float sum = (a0 ? v0 : 0.f) + (a1 ? v1 : 0.f);
    for (int off = 32; off; off >>= 1) sum += __shfl_xor(sum, off, 64);
    float deg = fmaxf(1.0f + sum, 1e-6f);          // +1: identity diagonal
    if (lane == 0) {
        float di = 1.0f / sqrtf(deg);
        dis[w]  = di;
        self[w] = di * di;
    }

    unsigned long long m0 = __ballot(a0);
    unsigned long long m1 = __ballot(a1);
    unsigned long long below = (1ull << lane) - 1ull;
    int n0 = __popcll(m0);
    if (a0) entries[base + __popcll(m0 & below)]      = make_uint2(key0, __float_as_uint(v0));
    if (a1) entries[base + n0 + __popcll(m1 & below)] = make_uint2(key1, __float_as_uint(v1));
    if (lane == 0) cnt_fin[w] = (uint32_t)(n0 + __popcll(m1));
}

// ---------------- kernel 3: fused SpMM + (X @ W^T) + optional GELU ------
// (round-9 verbatim) dword gathers, 16 independent in flight, 4 acc chains;
// in-lane normalization before broadcast; fused 2-row W-loop.
__global__ void k_layer(const float* __restrict__ Xin, const float* __restrict__ W,
                        float* __restrict__ Xout,
                        const uint32_t* __restrict__ cnt_fin, const uint2* __restrict__ entries,
                        const float* __restrict__ dis, const float* __restrict__ self,
                        int dogelu) {
    __shared__ float WT[64 * 65];     // WT[d*65+e] = W[e*64+d]; +1 pad: conflict-free
    int Lb = blockIdx.x;              // 4096 blocks
    int b  = Lb & 15;                 // batch -> XCD swizzle
    int rb = Lb >> 4;
    int t  = threadIdx.x;

    #pragma unroll
    for (int i = 0; i < 16; ++i) {
        int idx = i * 256 + t;
        WT[(idx & 63) * 65 + (idx >> 6)] = W[idx];
    }
    __syncthreads();

    int lane = t & 63;
    int wid  = t >> 6;
    const float* Xb   = Xin + (size_t)b * NNODE * DDIM;
    const char*  Xc   = (const char*)Xb + lane * 4;
    const float* disB = dis + (b << 11);

    float accv[2];
    #pragma unroll
    for (int rr = 0; rr < 2; ++rr) {
        int row = rb * 8 + wid * 2 + rr;
        int rg  = b * NNODE + row;
        int k   = (int)cnt_fin[rg];
        size_t base = (size_t)rg * SLOTS;

        uint32_t kA = 0u, vA = 0u, kB = 0u, vB = 0u;
        if (lane < k)      { uint2 kv = entries[base + lane];      kA = kv.x; vA = kv.y; }
        if (lane + 64 < k) { uint2 kv = entries[base + 64 + lane]; kB = kv.x; vB = kv.y; }

        // in-lane normalization before broadcast: off = col*256, w = dr*val*dis[col]
        float dr = disB[row];
        int   colA = (int)(kA & 2047u);
        uint32_t offA = (uint32_t)colA << 8;
        uint32_t wAu  = __float_as_uint(__uint_as_float(vA) * dr * disB[colA]);
        int   colB = (int)(kB & 2047u);
        uint32_t offB = (uint32_t)colB << 8;
        uint32_t wBu  = __float_as_uint(__uint_as_float(vB) * dr * disB[colB]);

        float acc0 = self[rg] * Xb[(size_t)row * DDIM + lane];   // identity term
        float acc1 = 0.f, acc2 = 0.f, acc3 = 0.f;

        int k0 = k < 64 ? k : 64;
        int e = 0;
        for (; e + 16 <= k0; e += 16) {            // 16 loads in flight
            float xv0, xv1, xv2, xv3, xv4, xv5, xv6, xv7;
            float xv8, xv9, xva, xvb, xvc, xvd, xve, xvf;
            float w0, w1, w2, w3, w4, w5, w6, w7;
            float w8, w9, wa, wb, wc, wd, we, wf;
            #define G(idx, X, Wv) { \
                uint32_t o = __builtin_amdgcn_readlane(offA, e + idx); \
                Wv = __uint_as_float(__builtin_amdgcn_readlane(wAu, e + idx)); \
                X = *(const float*)(Xc + o); }
            G(0, xv0, w0)  G(1, xv1, w1)  G(2, xv2, w2)  G(3, xv3, w3)
            G(4, xv4, w4)  G(5, xv5, w5)  G(6, xv6, w6)  G(7, xv7, w7)
            G(8, xv8, w8)  G(9, xv9, w9)  G(10, xva, wa) G(11, xvb, wb)
            G(12, xvc, wc) G(13, xvd, wd) G(14, xve, we) G(15, xvf, wf)
            #undef G
            acc0 = fmaf(w0, xv0, acc0); acc1 = fmaf(w1, xv1, acc1);
            acc2 = fmaf(w2, xv2, acc2); acc3 = fmaf(w3, xv3, acc3);
            acc0 = fmaf(w4, xv4, acc0); acc1 = fmaf(w5, xv5, acc1);
            acc2 = fmaf(w6, xv6, acc2); acc3 = fmaf(w7, xv7, acc3);
            acc0 = fmaf(w8, xv8, acc0); acc1 = fmaf(w9, xv9, acc1);
            acc2 = fmaf(wa, xva, acc2); acc3 = fmaf(wb, xvb, acc3);
            acc0 = fmaf(wc, xvc, acc0); acc1 = fmaf(wd, xvd, acc1);
            acc2 = fmaf(we, xve, acc2); acc3 = fmaf(wf, xvf, acc3);
        }
        for (; e + 4 <= k0; e += 4) {
            uint32_t o0 = __builtin_amdgcn_readlane(offA, e);
            uint32_t o1 = __builtin_amdgcn_readlane(offA, e + 1);
            uint32_t o2 = __builtin_amdgcn_readlane(offA, e + 2);
            uint32_t o3 = __builtin_amdgcn_readlane(offA, e + 3);
            float w0 = __uint_as_float(__builtin_amdgcn_readlane(wAu, e));
            float w1 = __uint_as_float(__builtin_amdgcn_readlane(wAu, e + 1));
            float w2 = __uint_as_float(__builtin_amdgcn_readlane(wAu, e + 2));
            float w3 = __uint_as_float(__builtin_amdgcn_readlane(wAu, e + 3));
            acc0 = fmaf(w0, *(const float*)(Xc + o0), acc0);
            acc1 = fmaf(w1, *(const float*)(Xc + o1), acc1);
            acc2 = fmaf(w2, *(const float*)(Xc + o2), acc2);
            acc3 = fmaf(w3, *(const float*)(Xc + o3), acc3);
        }
        for (; e < k0; ++e) {
            uint32_t o = __builtin_amdgcn_readlane(offA, e);
            float wv = __uint_as_float(__builtin_amdgcn_readlane(wAu, e));
            acc0 = fmaf(wv, *(const float*)(Xc + o), acc0);
        }
        for (e = 64; e < k; ++e) {                 // rare tail (k>64)
            uint32_t o = __builtin_amdgcn_readlane(offB, e - 64);
            float wv = __uint_as_float(__builtin_amdgcn_readlane(wBu, e - 64));
            acc1 = fmaf(wv, *(const float*)(Xc + o), acc1);
        }
        accv[rr] = (acc0 + acc1) + (acc2 + acc3);
    }

    // fused W-multiply: one WT read serves both rows
    float sa = accv[0], sb = accv[1];
    float ya = 0.f, yb = 0.f;
    #pragma unroll
    for (int d = 0; d < 64; ++d) {
        float wt = WT[d * 65 + lane];
        ya = fmaf(__uint_as_float(__builtin_amdgcn_readlane(__float_as_uint(sa), d)), wt, ya);
        yb = fmaf(__uint_as_float(__builtin_amdgcn_readlane(__float_as_uint(sb), d)), wt, yb);
    }
    if (dogelu) {
        ya = 0.5f * ya * (1.0f + erff(ya * 0.70710678118654752440f));
        yb = 0.5f * yb * (1.0f + erff(yb * 0.70710678118654752440f));
    }
    int row0 = rb * 8 + wid * 2;
    Xout[((size_t)b * NNODE + row0)     * DDIM + lane] = ya;
    Xout[((size_t)b * NNODE + row0 + 1) * DDIM + lane] = yb;
}

// ---------------- launch ------------------------------------------------
extern "C" void kernel_launch(void* const* d_in, const int* in_sizes, int n_in,
                              void* d_out, int out_size, void* d_ws, size_t ws_size,
                              hipStream_t stream) {
    const float* H  = (const float*)d_in[0];   // (B,N,D) fp32
    const int*   ei = (const int*)d_in[1];     // (B,2,E) int32
    const float* m  = (const float*)d_in[2];   // (B,E) fp32
    const float* W  = (const float*)d_in[3];   // (L,D,D) fp32
    float* out = (float*)d_out;                // (B,N,D) fp32

    char* ws = (char*)d_ws;
    uint32_t* cnt4    = (uint32_t*)ws;                                        // 512 KB (4 counts/row)
    uint32_t* cnt_fin = (uint32_t*)(ws + (512 << 10));                        // 128 KB
    float*    dis     = (float*)(ws + (640 << 10));                           // 128 KB
    float*    self    = (float*)(ws + (768 << 10));                           // 128 KB
    uint2*    entries = (uint2*)(ws + (896 << 10));                           // 32768*128*8 = 32 MB
    float*    X2      = (float*)(ws + (896 << 10) + (size_t)NROWS * SLOTS * 8);  // 8 MB

    k_build <<<BATCH * (NNODE / RPB) * 4, 512, 0, stream>>>(ei, m, cnt4, entries);
    k_dedupe<<<NROWS / 4, 256, 0, stream>>>(cnt4, entries, cnt_fin, dis, self);
    k_layer <<<4096, 256, 0, stream>>>(H,  W,        X2,  cnt_fin, entries, dis, self, 1);
    k_layer <<<4096, 256, 0, stream>>>(X2, W + 4096, out, cnt_fin, entries, dis, self, 0);
}